// Round 5
// baseline (278.311 us; speedup 1.0000x reference)
//
#include <hip/hip_runtime.h>
#include <math.h>

#define BINS 30

static constexpr int BLOCK  = 256;
static constexpr int GRID   = 1024;  // 4 resident blocks/CU (33 KiB LDS) x 256 CUs
static constexpr int SLOTS  = 32;    // 30 bins + slot 30 = trash (out-of-range), 31 pad
static constexpr int UNROLL = 4;     // float4 loads per array per chunk (8 KiB/wave per burst)

typedef float f32x4 __attribute__((ext_vector_type(4)));

__device__ __forceinline__ float wave_sum(float v) {
    #pragma unroll
    for (int o = 32; o > 0; o >>= 1) v += __shfl_xor(v, o, 64);
    return v;
}

// Per-thread private packed histograms in LDS: h[slot*256 + tid] holds
// x-count in bits 0..15 (+1), y-count in bits 16..31 (+65536).
// ds_add_u32 fire-and-forget; columns thread-private, bank = tid%32,
// 2-way within wave = free (m136). SQ_LDS_BANK_CONFLICT = 0 verified.
//
// R9 = the clean single-variable experiment R4 botched.
// Evidence chain:
//  - R2: hist speed IDENTICAL for L3-resident vs HBM-fed inputs -> not
//    BW-bound; suspect the nontemporal (cache-bypass) request path caps
//    per-CU streaming (~4.6 B/cyc).
//  - R3: ping-pong double-buffer + NT = neutral (258.6 ~ 258.4), harmless.
//  - R4: bundled NT-drop with sched_barrier(0); the barrier collapsed the
//    ping-pong (VGPR 52, hist 100us) = m141 repeat. NT never tested.
// R5: EXACT R3 code with __builtin_nontemporal_load -> plain loads.
// Zero reuse means L2 pollution is irrelevant; the 6.3 TB/s ceiling (m13)
// was measured with regular loads, and half the input is L3-resident.
// Exactness: per-thread per-slot x-count <= 128 < 2^16; per-block per-slot
// column sum <= 32768 < 2^16 -> packed u32 sums exact.
__global__ __launch_bounds__(BLOCK, 4) void hist_kernel(
        const float* __restrict__ x, const float* __restrict__ y,
        int n4, unsigned int* __restrict__ g_hist)
{
    __shared__ unsigned int h[SLOTS * BLOCK];     // 32 KiB
    __shared__ unsigned int partial[BLOCK];       // +1 KiB
    const int tid = threadIdx.x;

    #pragma unroll
    for (int i = 0; i < SLOTS; ++i) h[i * BLOCK + tid] = 0u;
    __syncthreads();

    const f32x4* __restrict__ x4 = (const f32x4*)x;
    const f32x4* __restrict__ y4 = (const f32x4*)y;

    // torch.histc: idx = floor((v+4)*3.75) clipped to [0,29]; |v|>4 (or NaN) -> trash slot 30
    #define PROC(v, inc) {                                              \
        float q = fmaf((v), 3.75f, 15.0f);                              \
        int idx = (int)q;                                               \
        idx = idx > 29 ? 29 : idx;        /* v == 4.0 -> last bin */    \
        bool valid = fabsf(v) <= 4.0f;                                  \
        int slot = valid ? idx : 30;                                    \
        atomicAdd(&h[slot * BLOCK + tid], (inc));  /* ds_add_u32 */     \
    }
    #define PROC4(f, inc) { PROC((f).x, inc) PROC((f).y, inc) PROC((f).z, inc) PROC((f).w, inc) }

    // Ping-pong register buffers -- names static, never runtime-indexed.
    f32x4 aA[UNROLL], bA[UNROLL], aB[UNROLL], bB[UNROLL];

    #define LOAD(S, c) {                                                     \
        _Pragma("unroll")                                                    \
        for (int j = 0; j < UNROLL; ++j) {                                   \
            a##S[j] = x4[(c) + j * BLOCK + tid];   /* regular cached load */ \
            b##S[j] = y4[(c) + j * BLOCK + tid];                             \
        } }
    #define CONSUME(S) {                                                     \
        _Pragma("unroll")                                                    \
        for (int j = 0; j < UNROLL; ++j) {                                   \
            PROC4(a##S[j], 1u)                                               \
            PROC4(b##S[j], 65536u)                                           \
        } }

    const int span    = GRID * BLOCK * UNROLL;   // float4 stride per chunk step
    const int iter_sz = BLOCK * UNROLL;
    int cA = blockIdx.x * iter_sz;

    if (cA + iter_sz <= n4) {
        LOAD(A, cA)
        for (;;) {
            const int cB = cA + span;
            const bool hasB = (cB + iter_sz <= n4);
            if (hasB) LOAD(B, cB)          // 8 loads in flight over CONSUME(A)
            CONSUME(A)
            if (!hasB) break;
            const int cN = cB + span;
            const bool hasA = (cN + iter_sz <= n4);
            if (hasA) LOAD(A, cN)          // 8 loads in flight over CONSUME(B)
            CONSUME(B)
            if (!hasA) break;
            cA = cN;
        }
    }

    // Tail: grid-stride over the residue region (empty for the benchmark).
    for (int i = (n4 / iter_sz) * iter_sz + blockIdx.x * BLOCK + tid; i < n4; i += GRID * BLOCK) {
        f32x4 a = x4[i], b = y4[i];
        PROC4(a, 1u)
        PROC4(b, 65536u)
    }
    #undef CONSUME
    #undef LOAD
    #undef PROC4
    #undef PROC
    __syncthreads();

    // Reduce 256 columns per slot (packed u32 sums exact).
    const int slot = tid & 31;
    const int c0   = (tid >> 5) * 32;
    unsigned int s = 0;
    #pragma unroll 8
    for (int c = 0; c < 32; ++c) {
        int col = c0 + ((c + tid) & 31);
        s += h[slot * BLOCK + col];
    }
    partial[tid] = s;
    __syncthreads();
    if (tid < 32) {
        unsigned int tot = 0;
        #pragma unroll
        for (int g = 0; g < 8; ++g) tot += partial[g * 32 + tid];
        if (tid < BINS) {
            atomicAdd(&g_hist[tid],      tot & 0xFFFFu);  // x histogram
            atomicAdd(&g_hist[32 + tid], tot >> 16);      // y histogram
        }
    }
}

__global__ void finalize_kernel(const unsigned int* __restrict__ g_hist,
                                float* __restrict__ out)
{
    const int t = threadIdx.x;
    const bool active = t < BINS;
    float hx = active ? (float)g_hist[t]      : 0.0f;
    float hy = active ? (float)g_hist[32 + t] : 0.0f;
    float hj = hx + hy;                      // joint = hist_x + hist_y exactly

    float Sx = wave_sum(hx);
    float Sy = wave_sum(hy);
    float Sj = wave_sum(hj);

    float px = hx / Sx;
    float py = hy / Sy;
    float jp = hj / Sj;

    // mi = 30 * sum_j jp_j*(log jp_j - log py_j) - (sum_j jp_j) * (sum_i log px_i)
    float term = active ? jp * (logf(jp) - logf(py)) : 0.0f;
    float lpx  = active ? logf(px) : 0.0f;
    float sjp  = wave_sum(active ? jp : 0.0f);

    float st = wave_sum(term);
    float sl = wave_sum(lpx);
    if (t == 0) out[0] = -((float)BINS * st - sjp * sl);
}

extern "C" void kernel_launch(void* const* d_in, const int* in_sizes, int n_in,
                              void* d_out, int out_size, void* d_ws, size_t ws_size,
                              hipStream_t stream) {
    const float* x = (const float*)d_in[0];
    const float* y = (const float*)d_in[1];
    const int n = in_sizes[0];               // 2^25, divisible by 4
    unsigned int* g_hist = (unsigned int*)d_ws;

    (void)hipMemsetAsync(d_ws, 0, 64 * sizeof(unsigned int), stream);  // ws is poisoned 0xAA
    hist_kernel<<<GRID, BLOCK, 0, stream>>>(x, y, n >> 2, g_hist);
    finalize_kernel<<<1, 64, 0, stream>>>(g_hist, (float*)d_out);
}

// Round 6
// 259.203 us; speedup vs baseline: 1.0737x; 1.0737x over previous
//
#include <hip/hip_runtime.h>
#include <math.h>

#define BINS 30

static constexpr int BLOCK  = 256;
static constexpr int GRID   = 1024;  // 4 resident blocks/CU (33 KiB LDS) x 256 CUs
static constexpr int SLOTS  = 32;    // 30 bins + slot 30 = trash (out-of-range), 31 pad
static constexpr int UNROLL = 4;     // float4 loads per array per chunk (8 KiB/wave per burst)

typedef float f32x4 __attribute__((ext_vector_type(4)));

__device__ __forceinline__ float wave_sum(float v) {
    #pragma unroll
    for (int o = 32; o > 0; o >>= 1) v += __shfl_xor(v, o, 64);
    return v;
}

// Per-thread private packed histograms in LDS: h[slot*256 + tid] holds
// x-count in bits 0..15 (+1), y-count in bits 16..31 (+65536).
// ds_add_u32 fire-and-forget; columns thread-private, bank = tid%32,
// 2-way within wave = free (m136). SQ_LDS_BANK_CONFLICT = 0 verified.
//
// R10 evidence chain (corrected):
//  - ERRATA: R2's "L3-resident dispatches ran same speed" was a rocprof
//    artifact -- that pass collected WRITE_SIZE only, FETCH was NaN. The
//    NT-request-path-cap theory built on it is retracted.
//  - Clean NT-vs-plain A/B (R3 vs R5, identical code): NT ~75us, plain
//    102-104us. NT WINS by ~27us -> keep nt.
//  - The real bug: VGPR_Count = 52/52/64 across R2/R4/R5 despite a 128
//    budget -- hipcc refuses to keep two 8-load buffers live and
//    serializes (sinks loads to uses). R3's ping-pong compiled to R0.
//    This is the Sec5 "compiler defeats source pipelining" lesson.
// R6: force the pipeline with the guide's verified recipe (T4 + rule 18):
//  - loads are asm volatile global_load_dwordx4 ... nt ("=&v" outputs ->
//    both buffers MUST stay allocated; volatile -> issue order pinned);
//  - consume gated by counted s_waitcnt vmcnt(8): the next chunk's 8
//    loads remain in flight across every consume phase (never drain to 0
//    mid-loop);
//  - ONE sched_barrier(0) after each wait (rule 18: VALU consumers would
//    otherwise hoist past an inline-asm waitcnt). NOT m141's
//    pin-everything (that was R4's mistake).
// Exactness: per-thread per-slot x-count <= 128 < 2^16; per-block per-slot
// column sum <= 32768 < 2^16 -> packed u32 sums exact.
__global__ __launch_bounds__(BLOCK, 4) void hist_kernel(
        const float* __restrict__ x, const float* __restrict__ y,
        int n4, unsigned int* __restrict__ g_hist)
{
    __shared__ unsigned int h[SLOTS * BLOCK];     // 32 KiB
    __shared__ unsigned int partial[BLOCK];       // +1 KiB
    const int tid = threadIdx.x;

    #pragma unroll
    for (int i = 0; i < SLOTS; ++i) h[i * BLOCK + tid] = 0u;
    __syncthreads();

    const f32x4* __restrict__ x4 = (const f32x4*)x;
    const f32x4* __restrict__ y4 = (const f32x4*)y;

    // torch.histc: idx = floor((v+4)*3.75) clipped to [0,29]; |v|>4 (or NaN) -> trash slot 30
    #define PROC(v, inc) {                                              \
        float q = fmaf((v), 3.75f, 15.0f);                              \
        int idx = (int)q;                                               \
        idx = idx > 29 ? 29 : idx;        /* v == 4.0 -> last bin */    \
        bool valid = fabsf(v) <= 4.0f;                                  \
        int slot = valid ? idx : 30;                                    \
        atomicAdd(&h[slot * BLOCK + tid], (inc));  /* ds_add_u32 */     \
    }
    #define PROC4(f, inc) { PROC((f).x, inc) PROC((f).y, inc) PROC((f).z, inc) PROC((f).w, inc) }

    // Ping-pong register buffers -- forced live by asm "=&v" outputs.
    f32x4 aA[UNROLL], bA[UNROLL], aB[UNROLL], bB[UNROLL];

    // Issue 8 independent dwordx4 NT loads; fire-and-forget (vmcnt-counted).
    #define LOAD_ASM(S, c) {                                                 \
        _Pragma("unroll")                                                    \
        for (int j = 0; j < UNROLL; ++j) {                                   \
            const f32x4* pa = &x4[(c) + j * BLOCK + tid];                    \
            const f32x4* pb = &y4[(c) + j * BLOCK + tid];                    \
            asm volatile("global_load_dwordx4 %0, %1, off nt"                \
                         : "=&v"(a##S[j]) : "v"(pa));                        \
            asm volatile("global_load_dwordx4 %0, %1, off nt"                \
                         : "=&v"(b##S[j]) : "v"(pb));                        \
        } }
    #define CONSUME(S) {                                                     \
        _Pragma("unroll")                                                    \
        for (int j = 0; j < UNROLL; ++j) {                                   \
            PROC4(a##S[j], 1u)                                               \
            PROC4(b##S[j], 65536u)                                           \
        } }
    // Counted wait: N loads may remain outstanding past this point.
    #define WAIT_VM(n) asm volatile("s_waitcnt vmcnt(" #n ")" ::: "memory")

    const int span    = GRID * BLOCK * UNROLL;   // float4 stride per chunk step
    const int iter_sz = BLOCK * UNROLL;
    const int nfull   = n4 / span;               // complete chunk rounds (8 for the bench)

    if (nfull > 0) {
        int cA = blockIdx.x * iter_sz;
        int done = 0;
        LOAD_ASM(A, cA)
        for (;;) {
            const int cB = cA + span;
            if (done + 1 < nfull) {
                LOAD_ASM(B, cB)          // 8 loads stay in flight...
                WAIT_VM(8);              // ...while A (oldest 8) completes
            } else {
                WAIT_VM(0);
            }
            __builtin_amdgcn_sched_barrier(0);   // rule 18: no VALU hoisting past the wait
            CONSUME(A)
            if (++done >= nfull) break;
            const int cN = cB + span;
            if (done + 1 < nfull) {
                LOAD_ASM(A, cN)
                WAIT_VM(8);
            } else {
                WAIT_VM(0);
            }
            __builtin_amdgcn_sched_barrier(0);
            CONSUME(B)
            if (++done >= nfull) break;
            cA = cN;
        }
    }

    // Tail: grid-stride over the residue region (empty for the benchmark).
    for (int i = nfull * span + blockIdx.x * BLOCK + tid; i < n4; i += GRID * BLOCK) {
        f32x4 a = x4[i], b = y4[i];
        PROC4(a, 1u)
        PROC4(b, 65536u)
    }
    #undef WAIT_VM
    #undef CONSUME
    #undef LOAD_ASM
    #undef PROC4
    #undef PROC
    __syncthreads();

    // Reduce 256 columns per slot (packed u32 sums exact).
    const int slot = tid & 31;
    const int c0   = (tid >> 5) * 32;
    unsigned int s = 0;
    #pragma unroll 8
    for (int c = 0; c < 32; ++c) {
        int col = c0 + ((c + tid) & 31);
        s += h[slot * BLOCK + col];
    }
    partial[tid] = s;
    __syncthreads();
    if (tid < 32) {
        unsigned int tot = 0;
        #pragma unroll
        for (int g = 0; g < 8; ++g) tot += partial[g * 32 + tid];
        if (tid < BINS) {
            atomicAdd(&g_hist[tid],      tot & 0xFFFFu);  // x histogram
            atomicAdd(&g_hist[32 + tid], tot >> 16);      // y histogram
        }
    }
}

__global__ void finalize_kernel(const unsigned int* __restrict__ g_hist,
                                float* __restrict__ out)
{
    const int t = threadIdx.x;
    const bool active = t < BINS;
    float hx = active ? (float)g_hist[t]      : 0.0f;
    float hy = active ? (float)g_hist[32 + t] : 0.0f;
    float hj = hx + hy;                      // joint = hist_x + hist_y exactly

    float Sx = wave_sum(hx);
    float Sy = wave_sum(hy);
    float Sj = wave_sum(hj);

    float px = hx / Sx;
    float py = hy / Sy;
    float jp = hj / Sj;

    // mi = 30 * sum_j jp_j*(log jp_j - log py_j) - (sum_j jp_j) * (sum_i log px_i)
    float term = active ? jp * (logf(jp) - logf(py)) : 0.0f;
    float lpx  = active ? logf(px) : 0.0f;
    float sjp  = wave_sum(active ? jp : 0.0f);

    float st = wave_sum(term);
    float sl = wave_sum(lpx);
    if (t == 0) out[0] = -((float)BINS * st - sjp * sl);
}

extern "C" void kernel_launch(void* const* d_in, const int* in_sizes, int n_in,
                              void* d_out, int out_size, void* d_ws, size_t ws_size,
                              hipStream_t stream) {
    const float* x = (const float*)d_in[0];
    const float* y = (const float*)d_in[1];
    const int n = in_sizes[0];               // 2^25, divisible by 4
    unsigned int* g_hist = (unsigned int*)d_ws;

    (void)hipMemsetAsync(d_ws, 0, 64 * sizeof(unsigned int), stream);  // ws is poisoned 0xAA
    hist_kernel<<<GRID, BLOCK, 0, stream>>>(x, y, n >> 2, g_hist);
    finalize_kernel<<<1, 64, 0, stream>>>(g_hist, (float*)d_out);
}